// Round 4
// baseline (616.102 us; speedup 1.0000x reference)
//
#include <hip/hip_runtime.h>
#include <hip/hip_bf16.h>
#include <stdint.h>

#define T_SEQ 2048
#define D_MODEL 2048
#define KV_DIM 512
#define NHEADS 16
#define HDIM 128
#define BATCH 4
#define MT (BATCH * T_SEQ)  // 8192 rows

typedef __attribute__((ext_vector_type(4))) float f32x4;
typedef __attribute__((ext_vector_type(8))) __bf16 bf16x8;
typedef __attribute__((ext_vector_type(8))) unsigned short u16x8;
typedef __attribute__((ext_vector_type(4))) unsigned short u16x4;

static __device__ __forceinline__ unsigned short f32_bf16(float f) {
  unsigned u = __float_as_uint(f);
  u += 0x7fff + ((u >> 16) & 1);  // RNE
  return (unsigned short)(u >> 16);
}

static __device__ __forceinline__ void gload_lds16(const void* g, void* l) {
  __builtin_amdgcn_global_load_lds(
      (__attribute__((address_space(1))) void*)(const_cast<void*>(g)),
      (__attribute__((address_space(3))) void*)l, 16, 0, 0);
}

static __device__ __forceinline__ f32x4 mfma16(bf16x8 a, bf16x8 b, f32x4 c) {
  return __builtin_amdgcn_mfma_f32_16x16x32_bf16(a, b, c, 0, 0, 0);
}

// ---------------- f32 -> bf16 convert (vectorized) ----------------
__global__ void cvt_kernel(const float* __restrict__ in, unsigned short* __restrict__ out, int n4) {
  int i = blockIdx.x * 256 + threadIdx.x;
  if (i >= n4) return;
  f32x4 v = ((const f32x4*)in)[i];
  u16x4 o;
#pragma unroll
  for (int j = 0; j < 4; ++j) o[j] = f32_bf16(v[j]);
  ((u16x4*)out)[i] = o;
}

// ---------------- W[K][N] f32 -> Wt[N][K] bf16 ----------------
__global__ void transpose_kernel(const float* __restrict__ W, unsigned short* __restrict__ Wt,
                                 int K, int N) {
  __shared__ float tile[32][33];
  int bx = blockIdx.x * 32;  // N
  int by = blockIdx.y * 32;  // K
  int tx = threadIdx.x, ty = threadIdx.y;
#pragma unroll
  for (int i = 0; i < 32; i += 8)
    tile[ty + i][tx] = W[(size_t)(by + ty + i) * N + bx + tx];
  __syncthreads();
#pragma unroll
  for (int i = 0; i < 32; i += 8)
    Wt[(size_t)(bx + ty + i) * K + by + tx] = f32_bf16(tile[tx][ty + i]);
}

// ---------------- C[M,N] = A[M,K] @ Bt[N,K]^T  (bf16 in, bf16/f32 out) ----------------
template <typename OutT, bool HAS_BIAS>
__global__ __launch_bounds__(256, 2) void gemm_bt_kernel(
    const unsigned short* __restrict__ A, const unsigned short* __restrict__ Bt,
    OutT* __restrict__ C, const float* __restrict__ bias, int M, int N, int K) {
  __shared__ unsigned short As[128 * 32];
  __shared__ unsigned short Bs[128 * 32];
  const int tid = threadIdx.x;
  const int wave = tid >> 6, lane = tid & 63;
  const int lr = lane & 15, lh = lane >> 4;
  const int wr = (wave >> 1) * 64, wc = (wave & 1) * 64;
  const size_t ar0 = (size_t)blockIdx.y * 128;
  const size_t br0 = (size_t)blockIdx.x * 128;

  f32x4 acc[4][4] = {};

  for (int k0 = 0; k0 < K; k0 += 32) {
#pragma unroll
    for (int is = 0; is < 2; ++is) {
      const int c = is * 4 + wave;  // 8 chunks of 1024B per tile
      const int u = c * 64 + lane;  // 16B unit index
      const int r = u >> 2;
      const int kk = (u & 3) * 8;
      gload_lds16(A + (ar0 + r) * K + (k0 + kk), (char*)As + c * 1024);
      gload_lds16(Bt + (br0 + r) * K + (k0 + kk), (char*)Bs + c * 1024);
    }
    __syncthreads();
    bf16x8 af[4], bf[4];
#pragma unroll
    for (int m = 0; m < 4; ++m)
      af[m] = *(const bf16x8*)&As[(wr + m * 16 + lr) * 32 + lh * 8];
#pragma unroll
    for (int n = 0; n < 4; ++n)
      bf[n] = *(const bf16x8*)&Bs[(wc + n * 16 + lr) * 32 + lh * 8];
#pragma unroll
    for (int m = 0; m < 4; ++m)
#pragma unroll
      for (int n = 0; n < 4; ++n)
        acc[m][n] = mfma16(af[m], bf[n], acc[m][n]);
    __syncthreads();
  }

#pragma unroll
  for (int m = 0; m < 4; ++m) {
#pragma unroll
    for (int n = 0; n < 4; ++n) {
      const size_t col = br0 + wc + n * 16 + lr;
      float bv = 0.0f;
      if constexpr (HAS_BIAS) bv = bias[col];
#pragma unroll
      for (int r = 0; r < 4; ++r) {
        const size_t row = ar0 + wr + m * 16 + lh * 4 + r;  // C/D: col=lane&15, row=(lane>>4)*4+reg
        const float val = acc[m][n][r] + bv;
        if constexpr (sizeof(OutT) == 2)
          ((unsigned short*)C)[row * N + col] = f32_bf16(val);
        else
          ((float*)C)[row * N + col] = val;
      }
    }
  }
}

// ---------------- causal GQA flash attention ----------------
// grid (T/64, H, B), block 256. Wave w owns q rows [qb+w*16, +16).
__global__ __launch_bounds__(256, 2) void attn_kernel(
    const unsigned short* __restrict__ q, const unsigned short* __restrict__ k,
    const unsigned short* __restrict__ v, unsigned short* __restrict__ ctx) {
  const int qt = blockIdx.x, h = blockIdx.y, b = blockIdx.z;
  const int g = h >> 2;  // P = 4 heads/group
  const int tid = threadIdx.x;
  const int wave = tid >> 6, lane = tid & 63;
  const int lr = lane & 15, lh = lane >> 4;
  const int qb = qt * 64;
  const int qwb = qb + wave * 16;

  __shared__ unsigned short Ks[64 * 128];   // K tile, XOR-swizzled in 16B units
  __shared__ unsigned short Vts[128 * 72];  // V^T, pad stride 72
  __shared__ unsigned short Ps[4][16 * 72]; // per-wave P, pad stride 72

  // Q fragments in registers: A-operand row = lane&15, k = (lane>>4)*8+j
  bf16x8 aq[4];
  {
    const unsigned short* qp =
        q + ((size_t)b * T_SEQ + qwb + lr) * D_MODEL + h * HDIM + lh * 8;
#pragma unroll
    for (int kk = 0; kk < 4; ++kk) aq[kk] = *(const bf16x8*)(qp + kk * 32);
  }

  f32x4 oacc[8] = {};
  float m_run[4], l_run[4];
#pragma unroll
  for (int r = 0; r < 4; ++r) { m_run[r] = -1e30f; l_run[r] = 0.0f; }

  const float scale = 0.08838834764831845f;  // 1/sqrt(128)

  for (int kv0 = 0; kv0 <= qb; kv0 += 64) {
    __syncthreads();  // previous tile's reads complete
    // --- K tile via global_load_lds, source pre-swizzled (unit ^= (row&7)) ---
#pragma unroll
    for (int is = 0; is < 4; ++is) {
      const int c = is * 4 + wave;
      const int u = c * 64 + lane;        // physical 16B unit
      const int vu = u ^ ((u >> 4) & 7);  // logical unit (involution, row-preserving)
      const int r = vu >> 4;
      const int cc = (vu & 15) * 8;
      gload_lds16(k + ((size_t)b * T_SEQ + kv0 + r) * KV_DIM + g * HDIM + cc,
                  (char*)Ks + c * 1024);
    }
    // --- V^T stage: 2 rows x 16 cols per thread, packed b32 writes ---
    {
      const int r0 = (tid & 31) * 2;
      const int c0 = (tid >> 5) * 16;
      const unsigned short* vp =
          v + ((size_t)b * T_SEQ + kv0 + r0) * KV_DIM + g * HDIM + c0;
      u16x8 va0 = *(const u16x8*)(vp);
      u16x8 va1 = *(const u16x8*)(vp + 8);
      u16x8 vb0 = *(const u16x8*)(vp + KV_DIM);
      u16x8 vb1 = *(const u16x8*)(vp + KV_DIM + 8);
#pragma unroll
      for (int j = 0; j < 8; ++j) {
        *(unsigned int*)&Vts[(c0 + j) * 72 + r0] =
            (unsigned int)va0[j] | ((unsigned int)vb0[j] << 16);
        *(unsigned int*)&Vts[(c0 + 8 + j) * 72 + r0] =
            (unsigned int)va1[j] | ((unsigned int)vb1[j] << 16);
      }
    }
    __syncthreads();

    // --- S = Q K^T : B-operand col = kv = lane&15, k = d ---
    f32x4 sacc[4] = {};
#pragma unroll
    for (int n = 0; n < 4; ++n) {
      const int rr = n * 16 + lr;
#pragma unroll
      for (int kk = 0; kk < 4; ++kk) {
        const int lu = rr * 16 + kk * 4 + lh;
        const int pu = lu ^ (rr & 7);
        bf16x8 bk = *(const bf16x8*)((const char*)Ks + pu * 16);
        sacc[n] = mfma16(aq[kk], bk, sacc[n]);
      }
    }

    // --- scale + causal mask (only diagonal tile can mask) ---
    float sv[4][4];
    const bool diag = (kv0 == qb);
#pragma unroll
    for (int n = 0; n < 4; ++n)
#pragma unroll
      for (int r = 0; r < 4; ++r) {
        float val = sacc[n][r] * scale;
        if (diag && (n * 16 + lr > wave * 16 + lh * 4 + r)) val = -1e30f;
        sv[n][r] = val;
      }

    // --- online softmax: rows live in (lane>>4)*4+reg; reduce across lane&15 ---
    float rmax[4];
#pragma unroll
    for (int r = 0; r < 4; ++r)
      rmax[r] = fmaxf(fmaxf(sv[0][r], sv[1][r]), fmaxf(sv[2][r], sv[3][r]));
#pragma unroll
    for (int off = 1; off < 16; off <<= 1)
#pragma unroll
      for (int r = 0; r < 4; ++r) rmax[r] = fmaxf(rmax[r], __shfl_xor(rmax[r], off));

    float alpha[4], rsum[4];
#pragma unroll
    for (int r = 0; r < 4; ++r) {
      const float mnew = fmaxf(m_run[r], rmax[r]);
      alpha[r] = __expf(m_run[r] - mnew);
      m_run[r] = mnew;
      rsum[r] = 0.0f;
    }

    unsigned short* Pw = &Ps[wave][0];
#pragma unroll
    for (int n = 0; n < 4; ++n)
#pragma unroll
      for (int r = 0; r < 4; ++r) {
        const float p = __expf(sv[n][r] - m_run[r]);
        rsum[r] += p;
        Pw[(lh * 4 + r) * 72 + n * 16 + lr] = f32_bf16(p);
      }

#pragma unroll
    for (int off = 1; off < 16; off <<= 1)
#pragma unroll
      for (int r = 0; r < 4; ++r) rsum[r] += __shfl_xor(rsum[r], off);

#pragma unroll
    for (int r = 0; r < 4; ++r) l_run[r] = l_run[r] * alpha[r] + rsum[r];
#pragma unroll
    for (int nd = 0; nd < 8; ++nd)
#pragma unroll
      for (int r = 0; r < 4; ++r) oacc[nd][r] *= alpha[r];

    // --- PV: A = P (row=lane&15=q, k=kv), B = V^T (col=d, k=kv) ---
#pragma unroll
    for (int ks = 0; ks < 2; ++ks) {
      u16x4 plo = *(const u16x4*)&Pw[lr * 72 + ks * 32 + lh * 8];
      u16x4 phi = *(const u16x4*)&Pw[lr * 72 + ks * 32 + lh * 8 + 4];
      u16x8 pc;
#pragma unroll
      for (int j = 0; j < 4; ++j) { pc[j] = plo[j]; pc[j + 4] = phi[j]; }
      const bf16x8 ap = __builtin_bit_cast(bf16x8, pc);
#pragma unroll
      for (int nd = 0; nd < 8; ++nd) {
        u16x4 vlo = *(const u16x4*)&Vts[(nd * 16 + lr) * 72 + ks * 32 + lh * 8];
        u16x4 vhi = *(const u16x4*)&Vts[(nd * 16 + lr) * 72 + ks * 32 + lh * 8 + 4];
        u16x8 vc;
#pragma unroll
        for (int j = 0; j < 4; ++j) { vc[j] = vlo[j]; vc[j + 4] = vhi[j]; }
        oacc[nd] = mfma16(ap, __builtin_bit_cast(bf16x8, vc), oacc[nd]);
      }
    }
  }

  float invl[4];
#pragma unroll
  for (int r = 0; r < 4; ++r) invl[r] = 1.0f / l_run[r];
  unsigned short* cp = ctx + ((size_t)b * T_SEQ + qwb) * D_MODEL + h * HDIM;
#pragma unroll
  for (int nd = 0; nd < 8; ++nd)
#pragma unroll
    for (int r = 0; r < 4; ++r)
      cp[(size_t)(lh * 4 + r) * D_MODEL + nd * 16 + lr] = f32_bf16(oacc[nd][r] * invl[r]);
}

// ---------------- launch ----------------
extern "C" void kernel_launch(void* const* d_in, const int* in_sizes, int n_in,
                              void* d_out, int out_size, void* d_ws, size_t ws_size,
                              hipStream_t stream) {
  const float* x = (const float*)d_in[0];
  const float* Wq = (const float*)d_in[1];
  const float* Wk = (const float*)d_in[2];
  const float* Wv = (const float*)d_in[3];
  const float* Wo = (const float*)d_in[4];
  const float* bo = (const float*)d_in[5];
  float* out = (float*)d_out;

  char* ws = (char*)d_ws;
  // bf16 workspace layout (100 MB total); ctx aliases xb (attn runs after all xb readers)
  unsigned short* xb = (unsigned short*)(ws + 0);           // 8192x2048
  unsigned short* ctx = (unsigned short*)(ws + 0);          // 8192x2048 (alias)
  unsigned short* qbuf = (unsigned short*)(ws + 33554432);  // 8192x2048
  unsigned short* kbuf = (unsigned short*)(ws + 67108864);  // 8192x512
  unsigned short* vbuf = (unsigned short*)(ws + 75497472);  // 8192x512
  unsigned short* WqT = (unsigned short*)(ws + 83886080);   // 2048x2048
  unsigned short* WkT = (unsigned short*)(ws + 92274688);   // 512x2048
  unsigned short* WvT = (unsigned short*)(ws + 94371840);   // 512x2048
  unsigned short* WoT = (unsigned short*)(ws + 96468992);   // 2048x2048

  const int n4 = MT * D_MODEL / 4;
  cvt_kernel<<<(n4 + 255) / 256, 256, 0, stream>>>(x, xb, n4);
  dim3 tb(32, 8);
  transpose_kernel<<<dim3(D_MODEL / 32, D_MODEL / 32), tb, 0, stream>>>(Wq, WqT, D_MODEL, D_MODEL);
  transpose_kernel<<<dim3(KV_DIM / 32, D_MODEL / 32), tb, 0, stream>>>(Wk, WkT, D_MODEL, KV_DIM);
  transpose_kernel<<<dim3(KV_DIM / 32, D_MODEL / 32), tb, 0, stream>>>(Wv, WvT, D_MODEL, KV_DIM);
  transpose_kernel<<<dim3(D_MODEL / 32, D_MODEL / 32), tb, 0, stream>>>(Wo, WoT, D_MODEL, D_MODEL);

  gemm_bt_kernel<unsigned short, false><<<dim3(D_MODEL / 128, MT / 128), 256, 0, stream>>>(
      xb, WqT, qbuf, nullptr, MT, D_MODEL, D_MODEL);
  gemm_bt_kernel<unsigned short, false><<<dim3(KV_DIM / 128, MT / 128), 256, 0, stream>>>(
      xb, WkT, kbuf, nullptr, MT, KV_DIM, D_MODEL);
  gemm_bt_kernel<unsigned short, false><<<dim3(KV_DIM / 128, MT / 128), 256, 0, stream>>>(
      xb, WvT, vbuf, nullptr, MT, KV_DIM, D_MODEL);

  attn_kernel<<<dim3(T_SEQ / 64, NHEADS, BATCH), 256, 0, stream>>>(qbuf, kbuf, vbuf, ctx);

  gemm_bt_kernel<float, true><<<dim3(D_MODEL / 128, MT / 128), 256, 0, stream>>>(
      ctx, WoT, out, bo, MT, D_MODEL, D_MODEL);
}

// Round 5
// 592.993 us; speedup vs baseline: 1.0390x; 1.0390x over previous
//
#include <hip/hip_runtime.h>
#include <hip/hip_bf16.h>
#include <stdint.h>

#define T_SEQ 2048
#define D_MODEL 2048
#define KV_DIM 512
#define NHEADS 16
#define HDIM 128
#define BATCH 4
#define MT (BATCH * T_SEQ)  // 8192 rows

typedef __attribute__((ext_vector_type(4))) float f32x4;
typedef __attribute__((ext_vector_type(8))) __bf16 bf16x8;
typedef __attribute__((ext_vector_type(8))) unsigned short u16x8;
typedef __attribute__((ext_vector_type(4))) unsigned short u16x4;

static __device__ __forceinline__ unsigned short f32_bf16(float f) {
  unsigned u = __float_as_uint(f);
  u += 0x7fff + ((u >> 16) & 1);  // RNE
  return (unsigned short)(u >> 16);
}

static __device__ __forceinline__ void gload_lds16(const void* g, void* l) {
  __builtin_amdgcn_global_load_lds(
      (__attribute__((address_space(1))) void*)(const_cast<void*>(g)),
      (__attribute__((address_space(3))) void*)l, 16, 0, 0);
}

static __device__ __forceinline__ f32x4 mfma16(bf16x8 a, bf16x8 b, f32x4 c) {
  return __builtin_amdgcn_mfma_f32_16x16x32_bf16(a, b, c, 0, 0, 0);
}

// swizzled [rows][8 units of 16B] u16-index helpers (unit ^= row&7)
#define VIDX(d, c) (((((d) << 3) + ((c) ^ ((d) & 7))) << 3))

// ---------------- f32 -> bf16 convert (vectorized) ----------------
__global__ void cvt_kernel(const float* __restrict__ in, unsigned short* __restrict__ out, int n4) {
  int i = blockIdx.x * 256 + threadIdx.x;
  if (i >= n4) return;
  f32x4 v = ((const f32x4*)in)[i];
  u16x4 o;
#pragma unroll
  for (int j = 0; j < 4; ++j) o[j] = f32_bf16(v[j]);
  ((u16x4*)out)[i] = o;
}

// ---------------- W[K][N] f32 -> Wt[N][K] bf16 ----------------
__global__ void transpose_kernel(const float* __restrict__ W, unsigned short* __restrict__ Wt,
                                 int K, int N) {
  __shared__ float tile[32][33];
  int bx = blockIdx.x * 32;  // N
  int by = blockIdx.y * 32;  // K
  int tx = threadIdx.x, ty = threadIdx.y;
#pragma unroll
  for (int i = 0; i < 32; i += 8)
    tile[ty + i][tx] = W[(size_t)(by + ty + i) * N + bx + tx];
  __syncthreads();
#pragma unroll
  for (int i = 0; i < 32; i += 8)
    Wt[(size_t)(bx + ty + i) * K + by + tx] = f32_bf16(tile[tx][ty + i]);
}

// ---------------- C[M,N] = A[M,K] @ Bt[N,K]^T  (bf16 in, bf16/f32 out) ----------------
template <typename OutT, bool HAS_BIAS>
__global__ __launch_bounds__(256, 2) void gemm_bt_kernel(
    const unsigned short* __restrict__ A, const unsigned short* __restrict__ Bt,
    OutT* __restrict__ C, const float* __restrict__ bias, int M, int N, int K) {
  __shared__ unsigned short As[128 * 32];
  __shared__ unsigned short Bs[128 * 32];
  const int tid = threadIdx.x;
  const int wave = tid >> 6, lane = tid & 63;
  const int lr = lane & 15, lh = lane >> 4;
  const int wr = (wave >> 1) * 64, wc = (wave & 1) * 64;
  const size_t ar0 = (size_t)blockIdx.y * 128;
  const size_t br0 = (size_t)blockIdx.x * 128;

  f32x4 acc[4][4] = {};

  for (int k0 = 0; k0 < K; k0 += 32) {
#pragma unroll
    for (int is = 0; is < 2; ++is) {
      const int c = is * 4 + wave;  // 8 chunks of 1024B per tile
      const int u = c * 64 + lane;  // 16B unit index
      const int r = u >> 2;
      const int kk = (u & 3) * 8;
      gload_lds16(A + (ar0 + r) * K + (k0 + kk), (char*)As + c * 1024);
      gload_lds16(Bt + (br0 + r) * K + (k0 + kk), (char*)Bs + c * 1024);
    }
    __syncthreads();
    bf16x8 af[4], bf[4];
#pragma unroll
    for (int m = 0; m < 4; ++m)
      af[m] = *(const bf16x8*)&As[(wr + m * 16 + lr) * 32 + lh * 8];
#pragma unroll
    for (int n = 0; n < 4; ++n)
      bf[n] = *(const bf16x8*)&Bs[(wc + n * 16 + lr) * 32 + lh * 8];
#pragma unroll
    for (int m = 0; m < 4; ++m)
#pragma unroll
      for (int n = 0; n < 4; ++n)
        acc[m][n] = mfma16(af[m], bf[n], acc[m][n]);
    __syncthreads();
  }

#pragma unroll
  for (int m = 0; m < 4; ++m) {
#pragma unroll
    for (int n = 0; n < 4; ++n) {
      const size_t col = br0 + wc + n * 16 + lr;
      float bv = 0.0f;
      if constexpr (HAS_BIAS) bv = bias[col];
#pragma unroll
      for (int r = 0; r < 4; ++r) {
        const size_t row = ar0 + wr + m * 16 + lh * 4 + r;  // C/D: col=lane&15, row=(lane>>4)*4+reg
        const float val = acc[m][n][r] + bv;
        if constexpr (sizeof(OutT) == 2)
          ((unsigned short*)C)[row * N + col] = f32_bf16(val);
        else
          ((float*)C)[row * N + col] = val;
      }
    }
  }
}

// ---------------- causal GQA flash attention ----------------
// 1024 blocks x 256 thr. Block handles QBLK=128 q-rows of one (b,h).
// Wave w: mrow0 = rows qb+w*16..+16, mrow1 = rows qb+64+w*16..+16.
// Block->(b,h,qt) decode is work-balanced: heavy qt dispatched first and
// each CU's expected 4 blocks sum to constant tile count.
__global__ __launch_bounds__(256, 2) void attn_kernel(
    const unsigned short* __restrict__ q, const unsigned short* __restrict__ k,
    const unsigned short* __restrict__ v, unsigned short* __restrict__ ctx) {
  const int lin = blockIdx.x;
  const int quad = lin >> 8, rem = lin & 255;
  const int combo = rem >> 2, j4 = rem & 3;
  int qt;
  if (quad == 0) qt = 15 - j4;
  else if (quad == 1) qt = j4;
  else if (quad == 2) qt = 11 - j4;
  else qt = 4 + j4;
  const int h = combo & 15, b = combo >> 4;
  const int g = h >> 2;  // 4 heads/group
  const int tid = threadIdx.x;
  const int wave = tid >> 6, lane = tid & 63;
  const int lr = lane & 15, lh = lane >> 4;
  const int qb = qt * 128;
  const int qrow0 = qb + wave * 16;
  const int qrow1 = qb + 64 + wave * 16;

  __shared__ unsigned short Ks[64 * 128];   // K tile, XOR-swizzled 16B units (row-preserving)
  __shared__ unsigned short Vts[128 * 64];  // V^T [d][kv], swizzled units
  __shared__ unsigned short Ps[4][32 * 64]; // per-wave P [32 q][64 kv], swizzled units
  unsigned short* Pw = &Ps[wave][0];

  // Q fragments: A row = lane&15, k = kk*32 + lh*8 + j
  bf16x8 aq[2][4];
  {
    const unsigned short* qp0 =
        q + ((size_t)b * T_SEQ + qrow0 + lr) * D_MODEL + h * HDIM + lh * 8;
    const unsigned short* qp1 =
        q + ((size_t)b * T_SEQ + qrow1 + lr) * D_MODEL + h * HDIM + lh * 8;
#pragma unroll
    for (int kk = 0; kk < 4; ++kk) {
      aq[0][kk] = *(const bf16x8*)(qp0 + kk * 32);
      aq[1][kk] = *(const bf16x8*)(qp1 + kk * 32);
    }
  }

  f32x4 oacc[2][8] = {};
  float m_run[2][4], l_run[2][4];
#pragma unroll
  for (int m = 0; m < 2; ++m)
#pragma unroll
    for (int r = 0; r < 4; ++r) { m_run[m][r] = -1e30f; l_run[m][r] = 0.0f; }

  const float scale = 0.08838834764831845f;  // 1/sqrt(128)
  const int nt = 2 * qt + 2;

  for (int t = 0; t < nt; ++t) {
    const int kv0 = t * 64;
    __syncthreads();  // previous tile's LDS reads complete
    // --- K tile via global_load_lds, pre-swizzled source (rule #21) ---
#pragma unroll
    for (int is = 0; is < 4; ++is) {
      const int c = is * 4 + wave;
      const int u = c * 64 + lane;        // physical 16B unit
      const int vu = u ^ ((u >> 4) & 7);  // logical unit (row-preserving involution)
      const int r = vu >> 4;
      const int cc = (vu & 15) * 8;
      gload_lds16(k + ((size_t)b * T_SEQ + kv0 + r) * KV_DIM + g * HDIM + cc,
                  (char*)Ks + c * 1024);
    }
    // --- V^T stage into swizzled layout: thread = 2 kv rows x 16 d cols ---
    {
      const int r0 = (tid & 31) * 2;
      const int c0 = (tid >> 5) * 16;
      const unsigned short* vp =
          v + ((size_t)b * T_SEQ + kv0 + r0) * KV_DIM + g * HDIM + c0;
      u16x8 va0 = *(const u16x8*)(vp);
      u16x8 va1 = *(const u16x8*)(vp + 8);
      u16x8 vb0 = *(const u16x8*)(vp + KV_DIM);
      u16x8 vb1 = *(const u16x8*)(vp + KV_DIM + 8);
      const int cu = r0 >> 3, cw = r0 & 7;
#pragma unroll
      for (int j = 0; j < 8; ++j) {
        const int d0 = c0 + j, d1 = c0 + 8 + j;
        *(unsigned int*)&Vts[VIDX(d0, cu) + cw] =
            (unsigned int)va0[j] | ((unsigned int)vb0[j] << 16);
        *(unsigned int*)&Vts[VIDX(d1, cu) + cw] =
            (unsigned int)va1[j] | ((unsigned int)vb1[j] << 16);
      }
    }
    __syncthreads();

    const bool live0 = (t < nt - 1);  // last tile is above-diagonal for all mrow0
    const bool mask0 = (t == nt - 2);
    const bool mask1 = (t == nt - 1);

    // --- S = Q K^T (B-fragments shared across both mrows) ---
    f32x4 s0[4] = {}, s1[4] = {};
#pragma unroll
    for (int n = 0; n < 4; ++n) {
      const int rr = n * 16 + lr;
#pragma unroll
      for (int kk = 0; kk < 4; ++kk) {
        const int lu = rr * 16 + kk * 4 + lh;
        const int pu = lu ^ (rr & 7);
        const bf16x8 bk = *(const bf16x8*)((const char*)Ks + pu * 16);
        if (live0) s0[n] = mfma16(aq[0][kk], bk, s0[n]);
        s1[n] = mfma16(aq[1][kk], bk, s1[n]);
      }
    }

    // --- mrow0: scale+mask, online softmax, P write ---
    if (live0) {
      float sv[4][4], rmax[4];
#pragma unroll
      for (int n = 0; n < 4; ++n)
#pragma unroll
        for (int r = 0; r < 4; ++r) {
          float val = s0[n][r] * scale;
          if (mask0 && (kv0 + n * 16 + lr > qrow0 + lh * 4 + r)) val = -1e30f;
          sv[n][r] = val;
        }
#pragma unroll
      for (int r = 0; r < 4; ++r)
        rmax[r] = fmaxf(fmaxf(sv[0][r], sv[1][r]), fmaxf(sv[2][r], sv[3][r]));
#pragma unroll
      for (int off = 1; off < 16; off <<= 1)
#pragma unroll
        for (int r = 0; r < 4; ++r) rmax[r] = fmaxf(rmax[r], __shfl_xor(rmax[r], off));
      float alpha[4], rsum[4];
#pragma unroll
      for (int r = 0; r < 4; ++r) {
        const float mnew = fmaxf(m_run[0][r], rmax[r]);
        alpha[r] = __expf(m_run[0][r] - mnew);
        m_run[0][r] = mnew;
        rsum[r] = 0.0f;
      }
#pragma unroll
      for (int n = 0; n < 4; ++n) {
        const int c = n * 2 + (lr >> 3);
#pragma unroll
        for (int r = 0; r < 4; ++r) {
          const float p = __expf(sv[n][r] - m_run[0][r]);
          rsum[r] += p;
          const int lq = lh * 4 + r;  // mrow0 rows 0..15
          Pw[((((lq) << 3) + (c ^ (lq & 7))) << 3) + (lr & 7)] = f32_bf16(p);
        }
      }
#pragma unroll
      for (int off = 1; off < 16; off <<= 1)
#pragma unroll
        for (int r = 0; r < 4; ++r) rsum[r] += __shfl_xor(rsum[r], off);
#pragma unroll
      for (int r = 0; r < 4; ++r) l_run[0][r] = l_run[0][r] * alpha[r] + rsum[r];
#pragma unroll
      for (int nd = 0; nd < 8; ++nd)
#pragma unroll
        for (int r = 0; r < 4; ++r) oacc[0][nd][r] *= alpha[r];
    }

    // --- mrow1 ---
    {
      float sv[4][4], rmax[4];
#pragma unroll
      for (int n = 0; n < 4; ++n)
#pragma unroll
        for (int r = 0; r < 4; ++r) {
          float val = s1[n][r] * scale;
          if (mask1 && (kv0 + n * 16 + lr > qrow1 + lh * 4 + r)) val = -1e30f;
          sv[n][r] = val;
        }
#pragma unroll
      for (int r = 0; r < 4; ++r)
        rmax[r] = fmaxf(fmaxf(sv[0][r], sv[1][r]), fmaxf(sv[2][r], sv[3][r]));
#pragma unroll
      for (int off = 1; off < 16; off <<= 1)
#pragma unroll
        for (int r = 0; r < 4; ++r) rmax[r] = fmaxf(rmax[r], __shfl_xor(rmax[r], off));
      float alpha[4], rsum[4];
#pragma unroll
      for (int r = 0; r < 4; ++r) {
        const float mnew = fmaxf(m_run[1][r], rmax[r]);
        alpha[r] = __expf(m_run[1][r] - mnew);
        m_run[1][r] = mnew;
        rsum[r] = 0.0f;
      }
#pragma unroll
      for (int n = 0; n < 4; ++n) {
        const int c = n * 2 + (lr >> 3);
#pragma unroll
        for (int r = 0; r < 4; ++r) {
          const float p = __expf(sv[n][r] - m_run[1][r]);
          rsum[r] += p;
          const int lq = 16 + lh * 4 + r;  // mrow1 rows 16..31
          Pw[((((lq) << 3) + (c ^ (lq & 7))) << 3) + (lr & 7)] = f32_bf16(p);
        }
      }
#pragma unroll
      for (int off = 1; off < 16; off <<= 1)
#pragma unroll
        for (int r = 0; r < 4; ++r) rsum[r] += __shfl_xor(rsum[r], off);
#pragma unroll
      for (int r = 0; r < 4; ++r) l_run[1][r] = l_run[1][r] * alpha[r] + rsum[r];
#pragma unroll
      for (int nd = 0; nd < 8; ++nd)
#pragma unroll
        for (int r = 0; r < 4; ++r) oacc[1][nd][r] *= alpha[r];
    }

    // --- PV: A = P (row=q local = lane&15), B = V^T (col=d), V-frags shared ---
    bf16x8 pa0[2], pa1[2];
#pragma unroll
    for (int ks = 0; ks < 2; ++ks) {
      const int c = ks * 4 + lh;
      if (live0) pa0[ks] = *(const bf16x8*)&Pw[(((lr) << 3) + (c ^ (lr & 7))) << 3];
      const int lq1 = 16 + lr;
      pa1[ks] = *(const bf16x8*)&Pw[(((lq1) << 3) + (c ^ (lr & 7))) << 3];
    }
#pragma unroll
    for (int ks = 0; ks < 2; ++ks) {
      const int c = ks * 4 + lh;
#pragma unroll
      for (int nd = 0; nd < 8; ++nd) {
        const int d = nd * 16 + lr;
        const bf16x8 vf = *(const bf16x8*)&Vts[VIDX(d, c)];
        if (live0) oacc[0][nd] = mfma16(pa0[ks], vf, oacc[0][nd]);
        oacc[1][nd] = mfma16(pa1[ks], vf, oacc[1][nd]);
      }
    }
  }

  // epilogue: normalize + store both mrows
#pragma unroll
  for (int m = 0; m < 2; ++m) {
    float invl[4];
#pragma unroll
    for (int r = 0; r < 4; ++r) invl[r] = 1.0f / l_run[m][r];
    const int qrow = (m == 0) ? qrow0 : qrow1;
    unsigned short* cp = ctx + ((size_t)b * T_SEQ + qrow) * D_MODEL + h * HDIM;
#pragma unroll
    for (int nd = 0; nd < 8; ++nd)
#pragma unroll
      for (int r = 0; r < 4; ++r)
        cp[(size_t)(lh * 4 + r) * D_MODEL + nd * 16 + lr] =
            f32_bf16(oacc[m][nd][r] * invl[r]);
  }
}

// ---------------- launch ----------------
extern "C" void kernel_launch(void* const* d_in, const int* in_sizes, int n_in,
                              void* d_out, int out_size, void* d_ws, size_t ws_size,
                              hipStream_t stream) {
  const float* x = (const float*)d_in[0];
  const float* Wq = (const float*)d_in[1];
  const float* Wk = (const float*)d_in[2];
  const float* Wv = (const float*)d_in[3];
  const float* Wo = (const float*)d_in[4];
  const float* bo = (const float*)d_in[5];
  float* out = (float*)d_out;

  char* ws = (char*)d_ws;
  // bf16 workspace layout (100 MB total); ctx aliases xb (attn runs after all xb readers)
  unsigned short* xb = (unsigned short*)(ws + 0);           // 8192x2048
  unsigned short* ctx = (unsigned short*)(ws + 0);          // 8192x2048 (alias)
  unsigned short* qbuf = (unsigned short*)(ws + 33554432);  // 8192x2048
  unsigned short* kbuf = (unsigned short*)(ws + 67108864);  // 8192x512
  unsigned short* vbuf = (unsigned short*)(ws + 75497472);  // 8192x512
  unsigned short* WqT = (unsigned short*)(ws + 83886080);   // 2048x2048
  unsigned short* WkT = (unsigned short*)(ws + 92274688);   // 512x2048
  unsigned short* WvT = (unsigned short*)(ws + 94371840);   // 512x2048
  unsigned short* WoT = (unsigned short*)(ws + 96468992);   // 2048x2048

  const int n4 = MT * D_MODEL / 4;
  cvt_kernel<<<(n4 + 255) / 256, 256, 0, stream>>>(x, xb, n4);
  dim3 tb(32, 8);
  transpose_kernel<<<dim3(D_MODEL / 32, D_MODEL / 32), tb, 0, stream>>>(Wq, WqT, D_MODEL, D_MODEL);
  transpose_kernel<<<dim3(KV_DIM / 32, D_MODEL / 32), tb, 0, stream>>>(Wk, WkT, D_MODEL, KV_DIM);
  transpose_kernel<<<dim3(KV_DIM / 32, D_MODEL / 32), tb, 0, stream>>>(Wv, WvT, D_MODEL, KV_DIM);
  transpose_kernel<<<dim3(D_MODEL / 32, D_MODEL / 32), tb, 0, stream>>>(Wo, WoT, D_MODEL, D_MODEL);

  gemm_bt_kernel<unsigned short, false><<<dim3(D_MODEL / 128, MT / 128), 256, 0, stream>>>(
      xb, WqT, qbuf, nullptr, MT, D_MODEL, D_MODEL);
  gemm_bt_kernel<unsigned short, false><<<dim3(KV_DIM / 128, MT / 128), 256, 0, stream>>>(
      xb, WkT, kbuf, nullptr, MT, KV_DIM, D_MODEL);
  gemm_bt_kernel<unsigned short, false><<<dim3(KV_DIM / 128, MT / 128), 256, 0, stream>>>(
      xb, WvT, vbuf, nullptr, MT, KV_DIM, D_MODEL);

  attn_kernel<<<1024, 256, 0, stream>>>(qbuf, kbuf, vbuf, ctx);

  gemm_bt_kernel<float, true><<<dim3(D_MODEL / 128, MT / 128), 256, 0, stream>>>(
      ctx, WoT, out, bo, MT, D_MODEL, D_MODEL);
}